// Round 1
// baseline (3648.332 us; speedup 1.0000x reference)
//
#include <hip/hip_runtime.h>

// SimpleGNN on MI355X — round 1 baseline.
// Structure: CSR build (once per call) -> per layer: 2x mean-aggregate + 2x fused
// fp32 GEMM (K=512 = [mean | x_self], epilogue bias + optional l2norm+ReLU).
// Buffers ping-pong between d_out and d_ws so final layer lands in d_out.

#define NNODES 50000
#define NEDGES 800000
#define DD 256
#define NLAYERS 5

// ---------------- CSR build ----------------

__global__ void hist_kernel(const int* __restrict__ dst, int n, int* __restrict__ cnt1) {
  int i = blockIdx.x * blockDim.x + threadIdx.x;
  if (i < n) atomicAdd(&cnt1[dst[i] + 1], 1);
}

// single-block inclusive scan over n (<= 1024*chunk) ints, in place
__global__ void scan_kernel(int* __restrict__ a, int n) {
  __shared__ int sums[1024];
  int tid = threadIdx.x;
  int chunk = (n + 1023) >> 10;
  int beg = tid * chunk;
  int end = min(beg + chunk, n);
  int s = 0;
  for (int i = beg; i < end; ++i) s += a[i];
  sums[tid] = s;
  __syncthreads();
  for (int d = 1; d < 1024; d <<= 1) {
    int v = (tid >= d) ? sums[tid - d] : 0;
    __syncthreads();
    sums[tid] += v;
    __syncthreads();
  }
  int run = (tid > 0) ? sums[tid - 1] : 0;
  for (int i = beg; i < end; ++i) { run += a[i]; a[i] = run; }
}

__global__ void fill_kernel(const int* __restrict__ src, const int* __restrict__ dst, int n,
                            const int* __restrict__ off, int* __restrict__ cur,
                            int* __restrict__ csr_src) {
  int i = blockIdx.x * blockDim.x + threadIdx.x;
  if (i < n) {
    int d = dst[i];
    int p = atomicAdd(&cur[d], 1);
    csr_src[off[d] + p] = src[i];
  }
}

// ---------------- aggregation: mean over CSR neighbors ----------------
// 1 wave per dst node; lane covers 4 dims (float4). Writes mean into target buf.
__global__ void sage_agg(const float* __restrict__ xsrc, const int* __restrict__ off,
                         const int* __restrict__ csr_src, float* __restrict__ meanout,
                         int ndst) {
  int node = blockIdx.x * 4 + (threadIdx.x >> 6);
  int lane = threadIdx.x & 63;
  if (node >= ndst) return;
  int o0 = off[node];
  int o1 = off[node + 1];
  float4 acc = make_float4(0.f, 0.f, 0.f, 0.f);
  for (int j = o0; j < o1; ++j) {
    int s = csr_src[j];
    float4 v = *(const float4*)(xsrc + (size_t)s * DD + (lane << 2));
    acc.x += v.x; acc.y += v.y; acc.z += v.z; acc.w += v.w;
  }
  float inv = 1.0f / fmaxf((float)(o1 - o0), 1.0f);
  acc.x *= inv; acc.y *= inv; acc.z *= inv; acc.w *= inv;
  *(float4*)(meanout + (size_t)node * DD + (lane << 2)) = acc;
}

// ---------------- fused SAGE GEMM ----------------
// out[m][n] = sum_k mean[m][k]*Wl[n][k] + sum_k xd[m][k]*Wr[n][k] + bias[n]
// optional epilogue: l2norm over n (full row in one wave) then ReLU.
// BM=32, BN=256 (full), BK=32; 256 threads; micro-tile 8 rows x 4 cols.
// In-place safe: out may alias mean (block owns its 32 rows exclusively).
#define BM 32
#define BK 32

__global__ __launch_bounds__(256) void sage_gemm(
    const float* __restrict__ mean, const float* __restrict__ xd,
    const float* __restrict__ Wl, const float* __restrict__ Wr,
    const float* __restrict__ bias, float* __restrict__ out, int M, int donorm) {
  __shared__ __align__(16) float Bl[BK][DD + 4];   // [k][n], stride 260 (16B-aligned rows)
  __shared__ __align__(16) float Al[BK][BM + 4];   // [k][m], stride 36

  int tid = threadIdx.x;
  int tr = tid >> 6;   // wave id 0..3 -> rows tr*8..tr*8+7
  int tc = tid & 63;   // lane -> cols 4*tc..4*tc+3
  int m0 = blockIdx.x * BM;

  float acc[8][4];
#pragma unroll
  for (int r = 0; r < 8; ++r)
#pragma unroll
    for (int i = 0; i < 4; ++i) acc[r][i] = 0.f;

#pragma unroll 1
  for (int c = 0; c < 16; ++c) {
    int kc = c * BK;                       // 0..480
    const float* W = (kc < DD) ? Wl : Wr;
    const float* Asrc = (kc < DD) ? mean : xd;
    int kw = kc & (DD - 1);

    // stage B chunk: 256 n x 32 k -> Bl[k][n]
#pragma unroll
    for (int j = 0; j < 8; ++j) {
      int idx = j * 256 + tid;
      int n = idx >> 3;
      int k4 = (idx & 7) << 2;
      float4 v = *(const float4*)(W + (size_t)n * DD + kw + k4);
      Bl[k4 + 0][n] = v.x; Bl[k4 + 1][n] = v.y; Bl[k4 + 2][n] = v.z; Bl[k4 + 3][n] = v.w;
    }
    // stage A chunk: 32 m x 32 k -> Al[k][m]
    {
      int m = tid >> 3;
      int k4 = (tid & 7) << 2;
      int mg = m0 + m; if (mg >= M) mg = M - 1;
      float4 v = *(const float4*)(Asrc + (size_t)mg * DD + kw + k4);
      Al[k4 + 0][m] = v.x; Al[k4 + 1][m] = v.y; Al[k4 + 2][m] = v.z; Al[k4 + 3][m] = v.w;
    }
    __syncthreads();

#pragma unroll
    for (int k = 0; k < BK; ++k) {
      float4 b = *(const float4*)&Bl[k][tc << 2];
      float a[8];
      *(float4*)&a[0] = *(const float4*)&Al[k][tr * 8];
      *(float4*)&a[4] = *(const float4*)&Al[k][tr * 8 + 4];
#pragma unroll
      for (int r = 0; r < 8; ++r) {
        acc[r][0] += a[r] * b.x;
        acc[r][1] += a[r] * b.y;
        acc[r][2] += a[r] * b.z;
        acc[r][3] += a[r] * b.w;
      }
    }
    __syncthreads();
  }

  // epilogue
  float4 bb = *(const float4*)(bias + (tc << 2));
#pragma unroll
  for (int r = 0; r < 8; ++r) {
    int row = m0 + tr * 8 + r;
    float4 o;
    o.x = acc[r][0] + bb.x;
    o.y = acc[r][1] + bb.y;
    o.z = acc[r][2] + bb.z;
    o.w = acc[r][3] + bb.w;
    if (donorm) {
      float s = o.x * o.x + o.y * o.y + o.z * o.z + o.w * o.w;
#pragma unroll
      for (int d = 1; d < 64; d <<= 1) s += __shfl_xor(s, d);
      float inv = 1.0f / fmaxf(sqrtf(s), 1e-12f);
      o.x = fmaxf(o.x * inv, 0.f);
      o.y = fmaxf(o.y * inv, 0.f);
      o.z = fmaxf(o.z * inv, 0.f);
      o.w = fmaxf(o.w * inv, 0.f);
    }
    if (row < M) *(float4*)(out + (size_t)row * DD + (tc << 2)) = o;
  }
}

// ---------------- launch ----------------

extern "C" void kernel_launch(void* const* d_in, const int* in_sizes, int n_in,
                              void* d_out, int out_size, void* d_ws, size_t ws_size,
                              hipStream_t stream) {
  const float* x_author = (const float*)d_in[0];
  const float* x_paper  = (const float*)d_in[1];
  const float* Wl = (const float*)d_in[2];   // [L,2,D,D]
  const float* bl = (const float*)d_in[3];   // [L,2,D]
  const float* Wr = (const float*)d_in[4];   // [L,2,D,D]
  const int* edge_ap = (const int*)d_in[5];  // [2,E] row0 src(author) row1 dst(paper)
  const int* edge_pa = (const int*)d_in[6];  // [2,E] row0 src(paper)  row1 dst(author)

  float* outA = (float*)d_out;                         // author half
  float* outP = (float*)d_out + (size_t)NNODES * DD;   // paper half

  // workspace carve-up
  char* w = (char*)d_ws;
  float* bufA = (float*)w;                  w += (size_t)NNODES * DD * 4;
  float* bufP = (float*)w;                  w += (size_t)NNODES * DD * 4;
  int* offAP = (int*)w;                     w += (size_t)(NNODES + 1) * 4;
  int* offPA = (int*)w;                     w += (size_t)(NNODES + 1) * 4;
  int* cur   = (int*)w;                     w += (size_t)2 * NNODES * 4;
  int* srcAP = (int*)w;                     w += (size_t)NEDGES * 4;
  int* srcPA = (int*)w;                     w += (size_t)NEDGES * 4;

  // zero offsets + cursors (contiguous region)
  hipMemsetAsync(offAP, 0, ((size_t)(NNODES + 1) * 2 + 2 * NNODES) * 4, stream);

  dim3 b256(256);
  dim3 gE((NEDGES + 255) / 256);
  hist_kernel<<<gE, b256, 0, stream>>>(edge_ap + NEDGES, NEDGES, offAP);
  hist_kernel<<<gE, b256, 0, stream>>>(edge_pa + NEDGES, NEDGES, offPA);
  scan_kernel<<<1, 1024, 0, stream>>>(offAP, NNODES + 1);
  scan_kernel<<<1, 1024, 0, stream>>>(offPA, NNODES + 1);
  fill_kernel<<<gE, b256, 0, stream>>>(edge_ap, edge_ap + NEDGES, NEDGES, offAP, cur, srcAP);
  fill_kernel<<<gE, b256, 0, stream>>>(edge_pa, edge_pa + NEDGES, NEDGES, offPA, cur + NNODES, srcPA);

  dim3 gAgg((NNODES + 3) / 4);
  dim3 gGemm((NNODES + BM - 1) / BM);

  for (int l = 0; l < NLAYERS; ++l) {
    // layer l: cur buffers -> tgt buffers.  targets: even l -> d_out halves, odd l -> ws bufs
    const float* ca;
    const float* cp;
    float* ta;
    float* tp;
    if (l == 0) { ca = x_author; cp = x_paper; }
    else if (l & 1) { ca = outA; cp = outP; }   // prev target was d_out (even l-1)
    else { ca = bufA; cp = bufP; }
    if (l & 1) { ta = bufA; tp = bufP; }
    else { ta = outA; tp = outP; }

    int donorm = (l < NLAYERS - 1) ? 1 : 0;
    const float* Wl0 = Wl + ((size_t)l * 2 + 0) * DD * DD;
    const float* Wr0 = Wr + ((size_t)l * 2 + 0) * DD * DD;
    const float* bl0 = bl + ((size_t)l * 2 + 0) * DD;
    const float* Wl1 = Wl + ((size_t)l * 2 + 1) * DD * DD;
    const float* Wr1 = Wr + ((size_t)l * 2 + 1) * DD * DD;
    const float* bl1 = bl + ((size_t)l * 2 + 1) * DD;

    // mean into target buffers (GEMM then overwrites them in place)
    sage_agg<<<gAgg, b256, 0, stream>>>(ca, offAP, srcAP, tp, NNODES);  // papers aggregate authors
    sage_agg<<<gAgg, b256, 0, stream>>>(cp, offPA, srcPA, ta, NNODES);  // authors aggregate papers

    sage_gemm<<<gGemm, b256, 0, stream>>>(tp, cp, Wl0, Wr0, bl0, tp, NNODES, donorm);
    sage_gemm<<<gGemm, b256, 0, stream>>>(ta, ca, Wl1, Wr1, bl1, ta, NNODES, donorm);
  }
}

// Round 3
// 2938.393 us; speedup vs baseline: 1.2416x; 1.2416x over previous
//
#include <hip/hip_runtime.h>

// SimpleGNN on MI355X — round 3: round-2 split-bf16 MFMA design + the missing
// barrier before the in-place epilogue write (donorm=0 path raced: waves wrote
// fp32 output over the self plane other waves were still reading as MFMA
// operands -> NaN). One __syncthreads() after the K-loop fixes it.

#define NNODES 50000
#define NEDGES 800000
#define DD 256
#define NLAYERS 5

typedef __attribute__((ext_vector_type(8))) short bf16x8;
typedef __attribute__((ext_vector_type(4))) float f32x4;

__device__ __forceinline__ ushort f2bf(float f) {
  uint u = __float_as_uint(f);
  u += 0x7fff + ((u >> 16) & 1);   // round-to-nearest-even
  return (ushort)(u >> 16);
}
__device__ __forceinline__ float bf2f(ushort h) { return __uint_as_float(((uint)h) << 16); }

// ---------------- CSR build ----------------

__global__ void hist_kernel(const int* __restrict__ dst, int n, int* __restrict__ cnt1) {
  int i = blockIdx.x * blockDim.x + threadIdx.x;
  if (i < n) atomicAdd(&cnt1[dst[i] + 1], 1);
}

__global__ void scan_kernel(int* __restrict__ a, int n) {
  __shared__ int sums[1024];
  int tid = threadIdx.x;
  int chunk = (n + 1023) >> 10;
  int beg = tid * chunk;
  int end = min(beg + chunk, n);
  int s = 0;
  for (int i = beg; i < end; ++i) s += a[i];
  sums[tid] = s;
  __syncthreads();
  for (int d = 1; d < 1024; d <<= 1) {
    int v = (tid >= d) ? sums[tid - d] : 0;
    __syncthreads();
    sums[tid] += v;
    __syncthreads();
  }
  int run = (tid > 0) ? sums[tid - 1] : 0;
  for (int i = beg; i < end; ++i) { run += a[i]; a[i] = run; }
}

__global__ void fill_kernel(const int* __restrict__ src, const int* __restrict__ dst, int n,
                            const int* __restrict__ off, int* __restrict__ cur,
                            int* __restrict__ csr_src) {
  int i = blockIdx.x * blockDim.x + threadIdx.x;
  if (i < n) {
    int d = dst[i];
    int p = atomicAdd(&cur[d], 1);
    csr_src[off[d] + p] = src[i];
  }
}

// ---------------- converts ----------------

__global__ void conv_w(const float* __restrict__ Wl, const float* __restrict__ Wr,
                       ushort* __restrict__ Whi, ushort* __restrict__ Wlo) {
  int idx = blockIdx.x * 256 + threadIdx.x;          // 10*256*512
  if (idx >= 10 * 256 * 512) return;
  int k = idx & 511;
  int n = (idx >> 9) & 255;
  int p = idx >> 17;
  float v = (k < 256) ? Wl[((size_t)p * 256 + n) * 256 + k]
                      : Wr[((size_t)p * 256 + n) * 256 + (k - 256)];
  ushort h = f2bf(v);
  ushort l = f2bf(v - bf2f(h));
  Whi[idx] = h;
  Wlo[idx] = l;
}

__global__ void conv_x(const float* __restrict__ x, uint* __restrict__ out, int n) {
  int i = blockIdx.x * 256 + threadIdx.x;
  if (i < n) {
    float f = x[i];
    ushort h = f2bf(f);
    ushort l = f2bf(f - bf2f(h));
    out[i] = ((uint)l << 16) | (uint)h;
  }
}

// ---------------- aggregation ----------------
// 1 wave per dst node, lane = 4 dims. Gathers packed hi/lo rows, writes mean hi/lo planes.
__global__ void sage_agg2(const uint* __restrict__ xsrc, const int* __restrict__ off,
                          const int* __restrict__ csr, ushort* __restrict__ mHi,
                          ushort* __restrict__ mLo, int ndst) {
  int node = blockIdx.x * 4 + (threadIdx.x >> 6);
  int lane = threadIdx.x & 63;
  if (node >= ndst) return;
  int o0 = off[node], o1 = off[node + 1];
  float a0 = 0.f, a1 = 0.f, a2 = 0.f, a3 = 0.f;
  int j = o0;
#define ACC4(U)                                                         \
  a0 += __uint_as_float((U).x << 16) + __uint_as_float((U).x & 0xffff0000u); \
  a1 += __uint_as_float((U).y << 16) + __uint_as_float((U).y & 0xffff0000u); \
  a2 += __uint_as_float((U).z << 16) + __uint_as_float((U).z & 0xffff0000u); \
  a3 += __uint_as_float((U).w << 16) + __uint_as_float((U).w & 0xffff0000u);
  for (; j + 3 < o1; j += 4) {
    int s0 = csr[j], s1 = csr[j + 1], s2 = csr[j + 2], s3 = csr[j + 3];
    uint4 u0 = *(const uint4*)(xsrc + (size_t)s0 * DD + (lane << 2));
    uint4 u1 = *(const uint4*)(xsrc + (size_t)s1 * DD + (lane << 2));
    uint4 u2 = *(const uint4*)(xsrc + (size_t)s2 * DD + (lane << 2));
    uint4 u3 = *(const uint4*)(xsrc + (size_t)s3 * DD + (lane << 2));
    ACC4(u0) ACC4(u1) ACC4(u2) ACC4(u3)
  }
  for (; j < o1; ++j) {
    int s = csr[j];
    uint4 u = *(const uint4*)(xsrc + (size_t)s * DD + (lane << 2));
    ACC4(u)
  }
#undef ACC4
  float inv = 1.0f / fmaxf((float)(o1 - o0), 1.0f);
  a0 *= inv; a1 *= inv; a2 *= inv; a3 *= inv;
  ushort4 h, l;
  h.x = f2bf(a0); l.x = f2bf(a0 - bf2f(h.x));
  h.y = f2bf(a1); l.y = f2bf(a1 - bf2f(h.y));
  h.z = f2bf(a2); l.z = f2bf(a2 - bf2f(h.z));
  h.w = f2bf(a3); l.w = f2bf(a3 - bf2f(h.w));
  *(ushort4*)(mHi + (size_t)node * DD + (lane << 2)) = h;
  *(ushort4*)(mLo + (size_t)node * DD + (lane << 2)) = l;
}

// ---------------- split-bf16 MFMA GEMM ----------------
// Block: 64 rows x 256 cols, 4 waves (wave w: cols [64w,64w+64)), K=512.
// A: k<256 from mean hi/lo planes; k>=256 from packed self (v_perm unpack).
// B: Whi/Wlo combined [n][512]. Direct-from-global (no LDS staging).
// In-place: selfNext/outF alias selfIl; barrier after K-loop makes it safe.
__global__ __launch_bounds__(256) void sage_gemm_mfma(
    const ushort* __restrict__ aggHi, const ushort* __restrict__ aggLo,
    const uint* __restrict__ selfIl,
    const ushort* __restrict__ Whi, const ushort* __restrict__ Wlo,
    const float* __restrict__ bias,
    float* __restrict__ outF, uint* __restrict__ selfNext,
    int M, int donorm) {
  __shared__ float part[64][5];
  int tid = threadIdx.x;
  int w = tid >> 6;
  int l = tid & 63;
  int l15 = l & 15;
  int kg = l >> 4;
  int m0 = blockIdx.x * 64;

  int mrow[4];
  int ncol[4];
#pragma unroll
  for (int i = 0; i < 4; ++i) {
    mrow[i] = min(m0 + i * 16 + l15, M - 1);
    ncol[i] = w * 64 + i * 16 + l15;
  }

  f32x4 acc[4][4];
#pragma unroll
  for (int a = 0; a < 4; ++a)
#pragma unroll
    for (int b = 0; b < 4; ++b) acc[a][b] = (f32x4){0.f, 0.f, 0.f, 0.f};

  const ushort* aH[4]; const ushort* aL[4];
  const ushort* bH[4]; const ushort* bL[4];
#pragma unroll
  for (int i = 0; i < 4; ++i) {
    aH[i] = aggHi + (size_t)mrow[i] * DD + kg * 8;
    aL[i] = aggLo + (size_t)mrow[i] * DD + kg * 8;
    bH[i] = Whi + (size_t)ncol[i] * 512 + kg * 8;
    bL[i] = Wlo + (size_t)ncol[i] * 512 + kg * 8;
  }

#define MFMA_BLOCK(AH, AL, BHv, BLv)                                              \
  _Pragma("unroll") for (int mf = 0; mf < 4; ++mf)                                \
      _Pragma("unroll") for (int nf = 0; nf < 4; ++nf)                            \
          acc[mf][nf] = __builtin_amdgcn_mfma_f32_16x16x32_bf16(AH[mf], BHv[nf],  \
                                                                acc[mf][nf], 0, 0, 0); \
  _Pragma("unroll") for (int mf = 0; mf < 4; ++mf)                                \
      _Pragma("unroll") for (int nf = 0; nf < 4; ++nf)                            \
          acc[mf][nf] = __builtin_amdgcn_mfma_f32_16x16x32_bf16(AH[mf], BLv[nf],  \
                                                                acc[mf][nf], 0, 0, 0); \
  _Pragma("unroll") for (int mf = 0; mf < 4; ++mf)                                \
      _Pragma("unroll") for (int nf = 0; nf < 4; ++nf)                            \
          acc[mf][nf] = __builtin_amdgcn_mfma_f32_16x16x32_bf16(AL[mf], BHv[nf],  \
                                                                acc[mf][nf], 0, 0, 0);

  // phase 1: k in [0,256) — mean planes
#pragma unroll 1
  for (int c = 0; c < 8; ++c) {
    bf16x8 ah[4], al[4], bh[4], blv[4];
#pragma unroll
    for (int i = 0; i < 4; ++i) {
      ah[i] = *(const bf16x8*)(aH[i]);
      al[i] = *(const bf16x8*)(aL[i]);
      bh[i] = *(const bf16x8*)(bH[i]);
      blv[i] = *(const bf16x8*)(bL[i]);
      aH[i] += 32; aL[i] += 32; bH[i] += 32; bL[i] += 32;
    }
    MFMA_BLOCK(ah, al, bh, blv)
  }

  // phase 2: k in [256,512) — packed self, v_perm unpack
  const uint* sp[4];
#pragma unroll
  for (int i = 0; i < 4; ++i) sp[i] = selfIl + (size_t)mrow[i] * DD + kg * 8;
#pragma unroll 1
  for (int c = 0; c < 8; ++c) {
    bf16x8 ah[4], al[4], bh[4], blv[4];
#pragma unroll
    for (int i = 0; i < 4; ++i) {
      uint4 u0 = *(const uint4*)(sp[i]);
      uint4 u1 = *(const uint4*)(sp[i] + 4);
      sp[i] += 32;
      union { uint u[4]; bf16x8 v; } H, L;
      H.u[0] = __builtin_amdgcn_perm(u0.y, u0.x, 0x05040100u);
      H.u[1] = __builtin_amdgcn_perm(u0.w, u0.z, 0x05040100u);
      H.u[2] = __builtin_amdgcn_perm(u1.y, u1.x, 0x05040100u);
      H.u[3] = __builtin_amdgcn_perm(u1.w, u1.z, 0x05040100u);
      L.u[0] = __builtin_amdgcn_perm(u0.y, u0.x, 0x07060302u);
      L.u[1] = __builtin_amdgcn_perm(u0.w, u0.z, 0x07060302u);
      L.u[2] = __builtin_amdgcn_perm(u1.y, u1.x, 0x07060302u);
      L.u[3] = __builtin_amdgcn_perm(u1.w, u1.z, 0x07060302u);
      ah[i] = H.v;
      al[i] = L.v;
      bh[i] = *(const bf16x8*)(bH[i]);
      blv[i] = *(const bf16x8*)(bL[i]);
      bH[i] += 32; bL[i] += 32;
    }
    MFMA_BLOCK(ah, al, bh, blv)
  }
#undef MFMA_BLOCK

  // All reads of selfIl (aliased by selfNext/outF) are done. Barrier BEFORE any
  // write so other waves' operand reads can't see this wave's epilogue stores.
  __syncthreads();

  // epilogue: bias
  float bv[4];
#pragma unroll
  for (int nf = 0; nf < 4; ++nf) bv[nf] = bias[ncol[nf]];
#pragma unroll
  for (int mf = 0; mf < 4; ++mf)
#pragma unroll
    for (int nf = 0; nf < 4; ++nf)
#pragma unroll
      for (int r = 0; r < 4; ++r) acc[mf][nf][r] += bv[nf];

  if (donorm) {
    float p[4][4];
#pragma unroll
    for (int mf = 0; mf < 4; ++mf)
#pragma unroll
      for (int r = 0; r < 4; ++r) {
        float s = 0.f;
#pragma unroll
        for (int nf = 0; nf < 4; ++nf) { float v = acc[mf][nf][r]; s += v * v; }
#pragma unroll
        for (int d = 1; d < 16; d <<= 1) s += __shfl_xor(s, d);
        p[mf][r] = s;
      }
    if (l15 == 0) {
#pragma unroll
      for (int mf = 0; mf < 4; ++mf)
#pragma unroll
        for (int r = 0; r < 4; ++r) part[mf * 16 + kg * 4 + r][w] = p[mf][r];
    }
    __syncthreads();
#pragma unroll
    for (int mf = 0; mf < 4; ++mf) {
#pragma unroll
      for (int r = 0; r < 4; ++r) {
        int rloc = mf * 16 + kg * 4 + r;
        int row = m0 + rloc;
        float s = part[rloc][0] + part[rloc][1] + part[rloc][2] + part[rloc][3];
        float invn = 1.0f / fmaxf(sqrtf(s), 1e-12f);
        if (row < M) {
#pragma unroll
          for (int nf = 0; nf < 4; ++nf) {
            float v = fmaxf(acc[mf][nf][r] * invn, 0.f);
            ushort h = f2bf(v);
            ushort lo = f2bf(v - bf2f(h));
            selfNext[(size_t)row * DD + ncol[nf]] = ((uint)lo << 16) | (uint)h;
          }
        }
      }
    }
  } else {
#pragma unroll
    for (int mf = 0; mf < 4; ++mf) {
#pragma unroll
      for (int r = 0; r < 4; ++r) {
        int row = m0 + mf * 16 + kg * 4 + r;
        if (row < M) {
#pragma unroll
          for (int nf = 0; nf < 4; ++nf)
            outF[(size_t)row * DD + ncol[nf]] = acc[mf][nf][r];
        }
      }
    }
  }
}

// ---------------- launch ----------------

extern "C" void kernel_launch(void* const* d_in, const int* in_sizes, int n_in,
                              void* d_out, int out_size, void* d_ws, size_t ws_size,
                              hipStream_t stream) {
  const float* x_author = (const float*)d_in[0];
  const float* x_paper  = (const float*)d_in[1];
  const float* Wl = (const float*)d_in[2];   // [L,2,D,D]
  const float* bl = (const float*)d_in[3];   // [L,2,D]
  const float* Wr = (const float*)d_in[4];   // [L,2,D,D]
  const int* edge_ap = (const int*)d_in[5];
  const int* edge_pa = (const int*)d_in[6];

  // self planes live in d_out (packed hi/lo); final fp32 output overwrites in place.
  uint* selfA = (uint*)d_out;
  uint* selfP = selfA + (size_t)NNODES * DD;
  float* outA = (float*)d_out;
  float* outP = outA + (size_t)NNODES * DD;

  char* wsp = (char*)d_ws;
  ushort* aggPhi = (ushort*)wsp; wsp += (size_t)NNODES * DD * 2;
  ushort* aggPlo = (ushort*)wsp; wsp += (size_t)NNODES * DD * 2;
  ushort* aggAhi = (ushort*)wsp; wsp += (size_t)NNODES * DD * 2;
  ushort* aggAlo = (ushort*)wsp; wsp += (size_t)NNODES * DD * 2;
  ushort* Whi_ = (ushort*)wsp;   wsp += (size_t)10 * 256 * 512 * 2;
  ushort* Wlo_ = (ushort*)wsp;   wsp += (size_t)10 * 256 * 512 * 2;
  int* offAP = (int*)wsp;        wsp += (size_t)(NNODES + 1) * 4;
  int* offPA = (int*)wsp;        wsp += (size_t)(NNODES + 1) * 4;
  int* cur   = (int*)wsp;        wsp += (size_t)2 * NNODES * 4;
  int* srcAP = (int*)wsp;        wsp += (size_t)NEDGES * 4;
  int* srcPA = (int*)wsp;        wsp += (size_t)NEDGES * 4;

  hipMemsetAsync(offAP, 0, ((size_t)(NNODES + 1) * 2 + 2 * NNODES) * 4, stream);

  dim3 b256(256);
  dim3 gE((NEDGES + 255) / 256);
  hist_kernel<<<gE, b256, 0, stream>>>(edge_ap + NEDGES, NEDGES, offAP);
  hist_kernel<<<gE, b256, 0, stream>>>(edge_pa + NEDGES, NEDGES, offPA);
  scan_kernel<<<1, 1024, 0, stream>>>(offAP, NNODES + 1);
  scan_kernel<<<1, 1024, 0, stream>>>(offPA, NNODES + 1);
  fill_kernel<<<gE, b256, 0, stream>>>(edge_ap, edge_ap + NEDGES, NEDGES, offAP, cur, srcAP);
  fill_kernel<<<gE, b256, 0, stream>>>(edge_pa, edge_pa + NEDGES, NEDGES, offPA, cur + NNODES, srcPA);

  conv_w<<<(10 * 256 * 512 + 255) / 256, b256, 0, stream>>>(Wl, Wr, Whi_, Wlo_);
  conv_x<<<(NNODES * DD + 255) / 256, b256, 0, stream>>>(x_author, selfA, NNODES * DD);
  conv_x<<<(NNODES * DD + 255) / 256, b256, 0, stream>>>(x_paper, selfP, NNODES * DD);

  dim3 gAgg((NNODES + 3) / 4);
  dim3 gGemm((NNODES + 63) / 64);

  for (int l = 0; l < NLAYERS; ++l) {
    int donorm = (l < NLAYERS - 1) ? 1 : 0;
    size_t p0 = (size_t)(l * 2 + 0);
    size_t p1 = (size_t)(l * 2 + 1);

    // aggP reads selfA; aggA reads selfP — both BEFORE gemms overwrite self planes
    sage_agg2<<<gAgg, b256, 0, stream>>>(selfA, offAP, srcAP, aggPhi, aggPlo, NNODES);
    sage_agg2<<<gAgg, b256, 0, stream>>>(selfP, offPA, srcPA, aggAhi, aggAlo, NNODES);

    sage_gemm_mfma<<<gGemm, b256, 0, stream>>>(
        aggPhi, aggPlo, selfP, Whi_ + p0 * 256 * 512, Wlo_ + p0 * 256 * 512,
        bl + p0 * DD, outP, selfP, NNODES, donorm);
    sage_gemm_mfma<<<gGemm, b256, 0, stream>>>(
        aggAhi, aggAlo, selfA, Whi_ + p1 * 256 * 512, Wlo_ + p1 * 256 * 512,
        bl + p1 * DD, outA, selfA, NNODES, donorm);
  }
}

// Round 5
// 2347.570 us; speedup vs baseline: 1.5541x; 1.2517x over previous
//
#include <hip/hip_runtime.h>

// SimpleGNN on MI355X — round 5: conservative LDS-staged GEMM.
// vs R4 (which GPU-faulted): LDS cut 133KB->64KB (B-only staged, double-buffered),
// no lane-clamped G2L sources (B staging is tid-linear), no launch_bounds VGPR cap,
// A (mean planes + packed self) read register-direct from global with an explicit
// one-chunk-ahead double-buffered prefetch (named reg sets pa/pb, static indexing).

#define NNODES 50000
#define NEDGES 800000
#define DD 256
#define NLAYERS 5

typedef __attribute__((ext_vector_type(8))) short bf16x8;
typedef __attribute__((ext_vector_type(4))) float f32x4;

__device__ __forceinline__ ushort f2bf(float f) {
  uint u = __float_as_uint(f);
  u += 0x7fff + ((u >> 16) & 1);   // round-to-nearest-even
  return (ushort)(u >> 16);
}
__device__ __forceinline__ float bf2f(ushort h) { return __uint_as_float(((uint)h) << 16); }

#define G2L(g, l)                                                        \
  __builtin_amdgcn_global_load_lds(                                      \
      (const __attribute__((address_space(1))) unsigned int*)(g),        \
      (__attribute__((address_space(3))) unsigned int*)(l), 16, 0, 0)

// ---------------- CSR build ----------------

__global__ void hist_kernel(const int* __restrict__ dst, int n, int* __restrict__ cnt1) {
  int i = blockIdx.x * blockDim.x + threadIdx.x;
  if (i < n) atomicAdd(&cnt1[dst[i] + 1], 1);
}

__global__ void scan_kernel(int* __restrict__ a, int n) {
  __shared__ int sums[1024];
  int tid = threadIdx.x;
  int chunk = (n + 1023) >> 10;
  int beg = tid * chunk;
  int end = min(beg + chunk, n);
  int s = 0;
  for (int i = beg; i < end; ++i) s += a[i];
  sums[tid] = s;
  __syncthreads();
  for (int d = 1; d < 1024; d <<= 1) {
    int v = (tid >= d) ? sums[tid - d] : 0;
    __syncthreads();
    sums[tid] += v;
    __syncthreads();
  }
  int run = (tid > 0) ? sums[tid - 1] : 0;
  for (int i = beg; i < end; ++i) { run += a[i]; a[i] = run; }
}

__global__ void fill_kernel(const int* __restrict__ src, const int* __restrict__ dst, int n,
                            const int* __restrict__ off, int* __restrict__ cur,
                            int* __restrict__ csr_src) {
  int i = blockIdx.x * blockDim.x + threadIdx.x;
  if (i < n) {
    int d = dst[i];
    int p = atomicAdd(&cur[d], 1);
    csr_src[off[d] + p] = src[i];
  }
}

// ---------------- converts ----------------
// W pre-swizzled into staged-chunk order: plane p, k-chunk kci (0..15), chunk c (0..1023):
//   q=c>>6, kg=(c>>4)&3, l=c&15 ; n = q*16+l, k = kci*32+kg*8+j  (j=0..7)
//   -> WhiSw[((p*16+kci)*1024 + c)*8 + j]
__global__ void conv_w_sw(const float* __restrict__ Wl, const float* __restrict__ Wr,
                          ushort* __restrict__ WhiSw, ushort* __restrict__ WloSw) {
  int idx = blockIdx.x * 256 + threadIdx.x;    // 10*16*1024 = 163840 chunks
  if (idx >= 163840) return;
  int p = idx >> 14;
  int rem = idx & 16383;
  int kci = rem >> 10;
  int c = rem & 1023;
  int q = c >> 6, kg = (c >> 4) & 3, l = c & 15;
  int n = q * 16 + l;
  int kb = kci * 32 + kg * 8;
  union { ushort s[8]; uint4 v; } H, L;
#pragma unroll
  for (int j = 0; j < 8; ++j) {
    int k = kb + j;
    float v = (k < 256) ? Wl[((size_t)p * 256 + n) * 256 + k]
                        : Wr[((size_t)p * 256 + n) * 256 + (k - 256)];
    ushort h = f2bf(v);
    H.s[j] = h;
    L.s[j] = f2bf(v - bf2f(h));
  }
  *(uint4*)(WhiSw + (size_t)idx * 8) = H.v;
  *(uint4*)(WloSw + (size_t)idx * 8) = L.v;
}

__global__ void conv_x(const float* __restrict__ x, uint* __restrict__ out, int n) {
  int i = blockIdx.x * 256 + threadIdx.x;
  if (i < n) {
    float f = x[i];
    ushort h = f2bf(f);
    ushort l = f2bf(f - bf2f(h));
    out[i] = ((uint)l << 16) | (uint)h;
  }
}

// ---------------- aggregation (unchanged, R3-proven) ----------------

__global__ void sage_agg2(const uint* __restrict__ xsrc, const int* __restrict__ off,
                          const int* __restrict__ csr, ushort* __restrict__ mHi,
                          ushort* __restrict__ mLo, int ndst) {
  int node = blockIdx.x * 4 + (threadIdx.x >> 6);
  int lane = threadIdx.x & 63;
  if (node >= ndst) return;
  int o0 = off[node], o1 = off[node + 1];
  float a0 = 0.f, a1 = 0.f, a2 = 0.f, a3 = 0.f;
  int j = o0;
#define ACC4(U)                                                         \
  a0 += __uint_as_float((U).x << 16) + __uint_as_float((U).x & 0xffff0000u); \
  a1 += __uint_as_float((U).y << 16) + __uint_as_float((U).y & 0xffff0000u); \
  a2 += __uint_as_float((U).z << 16) + __uint_as_float((U).z & 0xffff0000u); \
  a3 += __uint_as_float((U).w << 16) + __uint_as_float((U).w & 0xffff0000u);
  for (; j + 3 < o1; j += 4) {
    int s0 = csr[j], s1 = csr[j + 1], s2 = csr[j + 2], s3 = csr[j + 3];
    uint4 u0 = *(const uint4*)(xsrc + (size_t)s0 * DD + (lane << 2));
    uint4 u1 = *(const uint4*)(xsrc + (size_t)s1 * DD + (lane << 2));
    uint4 u2 = *(const uint4*)(xsrc + (size_t)s2 * DD + (lane << 2));
    uint4 u3 = *(const uint4*)(xsrc + (size_t)s3 * DD + (lane << 2));
    ACC4(u0) ACC4(u1) ACC4(u2) ACC4(u3)
  }
  for (; j < o1; ++j) {
    int s = csr[j];
    uint4 u = *(const uint4*)(xsrc + (size_t)s * DD + (lane << 2));
    ACC4(u)
  }
#undef ACC4
  float inv = 1.0f / fmaxf((float)(o1 - o0), 1.0f);
  a0 *= inv; a1 *= inv; a2 *= inv; a3 *= inv;
  ushort4 h, l;
  h.x = f2bf(a0); l.x = f2bf(a0 - bf2f(h.x));
  h.y = f2bf(a1); l.y = f2bf(a1 - bf2f(h.y));
  h.z = f2bf(a2); l.z = f2bf(a2 - bf2f(h.z));
  h.w = f2bf(a3); l.w = f2bf(a3 - bf2f(h.w));
  *(ushort4*)(mHi + (size_t)node * DD + (lane << 2)) = h;
  *(ushort4*)(mLo + (size_t)node * DD + (lane << 2)) = l;
}

// ---------------- B-staged split-bf16 MFMA GEMM ----------------
// Block 128 rows x 256 cols, 8 waves (wr=w>>1: 32-row quadrant; wc=w&1: 128-col half).
// K=512 in 16 chunks of 32. B double-buffered in LDS (2x32KB = 64KB exactly):
//   half-buf layout: [0,16K) B-hi chunks (idx = (n&~15)*4 + kg*16 + l15), [16K,32K) B-lo.
// A register-direct from global, one chunk prefetched ahead (pa/pb named sets).
__global__ __launch_bounds__(512) void sage_gemm_v3(
    const ushort* __restrict__ aggHi, const ushort* __restrict__ aggLo,
    const uint* __restrict__ selfIl,
    const ushort* __restrict__ WhiSw, const ushort* __restrict__ WloSw,
    const float* __restrict__ bias,
    float* __restrict__ outF, uint* __restrict__ selfNext,
    int M, int donorm) {
  __shared__ __align__(16) char smem[65536];

  int tid = threadIdx.x;
  int lane = tid & 63;
  int l15 = lane & 15;
  int kg = lane >> 4;
  int w = tid >> 6;
  int wr = w >> 1;
  int wc = w & 1;
  int m0 = blockIdx.x * 128;

  int arow[2];
#pragma unroll
  for (int mf = 0; mf < 2; ++mf) arow[mf] = min(m0 + wr * 32 + mf * 16 + l15, M - 1);

  f32x4 acc[2][8];
#pragma unroll
  for (int a = 0; a < 2; ++a)
#pragma unroll
    for (int b = 0; b < 8; ++b) acc[a][b] = (f32x4){0.f, 0.f, 0.f, 0.f};

  uint4 pa[2][2], pb[2][2];

#define STAGEB(lb, kci_)                                                       \
  do {                                                                         \
    char* wbS = (lb) + (tid & ~63) * 16;                                       \
    const ushort* ghS = WhiSw + (size_t)(kci_) * 8192 + (size_t)tid * 8;       \
    const ushort* glS = WloSw + (size_t)(kci_) * 8192 + (size_t)tid * 8;       \
    G2L(ghS, wbS);                                                             \
    G2L(ghS + 4096, wbS + 8192);                                               \
    G2L(glS, wbS + 16384);                                                     \
    G2L(glS + 4096, wbS + 24576);                                              \
  } while (0)

#define LOADA(P, kci_)                                                          \
  do {                                                                          \
    int kciL = (kci_);                                                          \
    if (kciL < 8) {                                                             \
      _Pragma("unroll") for (int mf = 0; mf < 2; ++mf) {                        \
        P[mf][0] = *(const uint4*)(aggHi + (size_t)arow[mf] * 256 + kciL * 32 + kg * 8); \
        P[mf][1] = *(const uint4*)(aggLo + (size_t)arow[mf] * 256 + kciL * 32 + kg * 8); \
      }                                                                         \
    } else {                                                                    \
      _Pragma("unroll") for (int mf = 0; mf < 2; ++mf) {                        \
        const uint* qL = selfIl + (size_t)arow[mf] * 256 + (kciL - 8) * 32 + kg * 8; \
        P[mf][0] = *(const uint4*)qL;                                           \
        P[mf][1] = *(const uint4*)(qL + 4);                                     \
      }                                                                         \
    }                                                                           \
  } while (0)

#define COMPUTE(P, kci_, lb)                                                    \
  do {                                                                          \
    int kciC = (kci_);                                                          \
    const char* lbC = (lb);                                                     \
    bf16x8 ahC[2], alC[2];                                                      \
    if (kciC < 8) {                                                             \
      _Pragma("unroll") for (int mf = 0; mf < 2; ++mf) {                        \
        union { uint4 u; bf16x8 v; } cvh, cvl;                                  \
        cvh.u = P[mf][0]; cvl.u = P[mf][1];                                     \
        ahC[mf] = cvh.v; alC[mf] = cvl.v;                                       \
      }                                                                         \
    } else {                                                                    \
      _Pragma("unroll") for (int mf = 0; mf < 2; ++mf) {                        \
        uint4 u0C = P[mf][0], u1C = P[mf][1];                                   \
        union { uint u[4]; bf16x8 v; } HC, LC;                                  \
        HC.u[0] = __builtin_amdgcn_perm(u0C.y, u0C.x, 0x05040100u);             \
        HC.u[1] = __builtin_amdgcn_perm(u0C.w, u0C.z, 0x05040100u);             \
        HC.u[2] = __builtin_amdgcn_perm(u1C.y, u1C.x, 0x05040100u);             \
        HC.u[3] = __builtin_amdgcn_perm(u1C.w, u1C.z, 0x05040100u);             \
        LC.u[0] = __builtin_amdgcn_perm(u0C.y, u0C.x, 0x07060302u);             \
        LC.u[1] = __builtin_amdgcn_perm(u0C.w, u0C.z, 0x07060302u);             \
        LC.u[2] = __builtin_amdgcn_perm(u1C.y, u1C.x, 0x07060302u);             \
        LC.u[3] = __builtin_amdgcn_perm(u1C.w, u1C.z, 0x07060302u);             \
        ahC[mf] = HC.v; alC[mf] = LC.v;                                         \
      }                                                                         \
    }                                                                           \
    _Pragma("unroll") for (int nf = 0; nf < 8; ++nf) {                          \
      int boffC = (wc * 128 + nf * 16) * 64 + lane * 16;                        \
      bf16x8 bhC = *(const bf16x8*)(lbC + boffC);                               \
      bf16x8 blC = *(const bf16x8*)(lbC + 16384 + boffC);                       \
      _Pragma("unroll") for (int mf = 0; mf < 2; ++mf)                          \
        acc[mf][nf] = __builtin_amdgcn_mfma_f32_16x16x32_bf16(ahC[mf], bhC, acc[mf][nf], 0, 0, 0); \
      _Pragma("unroll") for (int mf = 0; mf < 2; ++mf)                          \
        acc[mf][nf] = __builtin_amdgcn_mfma_f32_16x16x32_bf16(ahC[mf], blC, acc[mf][nf], 0, 0, 0); \
      _Pragma("unroll") for (int mf = 0; mf < 2; ++mf)                          \
        acc[mf][nf] = __builtin_amdgcn_mfma_f32_16x16x32_bf16(alC[mf], bhC, acc[mf][nf], 0, 0, 0); \
    }                                                                           \
  } while (0)

  STAGEB(smem, 0);
  LOADA(pa, 0);
  __syncthreads();

#pragma unroll 1
  for (int it = 0; it < 8; ++it) {
    int kA = it * 2, kB = it * 2 + 1;
    STAGEB(smem + 32768, kB);
    LOADA(pb, kB);
    COMPUTE(pa, kA, smem);
    __syncthreads();
    if (it < 7) {
      STAGEB(smem, kA + 2);
      LOADA(pa, kA + 2);
    }
    COMPUTE(pb, kB, smem + 32768);
    __syncthreads();
  }
#undef STAGEB
#undef LOADA
#undef COMPUTE

  // ---- epilogue (loop-final barrier ordered all selfIl reads before writes) ----
  float* part = (float*)smem;   // reuse LDS: [128][2] partial norm sums

  float bv[8];
#pragma unroll
  for (int nf = 0; nf < 8; ++nf) bv[nf] = bias[wc * 128 + nf * 16 + l15];
#pragma unroll
  for (int mf = 0; mf < 2; ++mf)
#pragma unroll
    for (int nf = 0; nf < 8; ++nf)
#pragma unroll
      for (int r = 0; r < 4; ++r) acc[mf][nf][r] += bv[nf];

  if (donorm) {
#pragma unroll
    for (int mf = 0; mf < 2; ++mf)
#pragma unroll
      for (int r = 0; r < 4; ++r) {
        float s = 0.f;
#pragma unroll
        for (int nf = 0; nf < 8; ++nf) { float v = acc[mf][nf][r]; s += v * v; }
#pragma unroll
        for (int d = 1; d < 16; d <<= 1) s += __shfl_xor(s, d);
        if (l15 == 0) part[(wr * 32 + mf * 16 + kg * 4 + r) * 2 + wc] = s;
      }
    __syncthreads();
#pragma unroll
    for (int mf = 0; mf < 2; ++mf) {
#pragma unroll
      for (int r = 0; r < 4; ++r) {
        int rloc = wr * 32 + mf * 16 + kg * 4 + r;
        int row = m0 + rloc;
        float s = part[rloc * 2 + 0] + part[rloc * 2 + 1];
        float invn = 1.0f / fmaxf(sqrtf(s), 1e-12f);
        if (row < M) {
#pragma unroll
          for (int nf = 0; nf < 8; ++nf) {
            float v = fmaxf(acc[mf][nf][r] * invn, 0.f);
            ushort h = f2bf(v);
            ushort lo = f2bf(v - bf2f(h));
            selfNext[(size_t)row * DD + wc * 128 + nf * 16 + l15] = ((uint)lo << 16) | (uint)h;
          }
        }
      }
    }
  } else {
#pragma unroll
    for (int mf = 0; mf < 2; ++mf) {
#pragma unroll
      for (int r = 0; r < 4; ++r) {
        int row = m0 + wr * 32 + mf * 16 + kg * 4 + r;
        if (row < M) {
#pragma unroll
          for (int nf = 0; nf < 8; ++nf)
            outF[(size_t)row * DD + wc * 128 + nf * 16 + l15] = acc[mf][nf][r];
        }
      }
    }
  }
}

// ---------------- launch ----------------

extern "C" void kernel_launch(void* const* d_in, const int* in_sizes, int n_in,
                              void* d_out, int out_size, void* d_ws, size_t ws_size,
                              hipStream_t stream) {
  const float* x_author = (const float*)d_in[0];
  const float* x_paper  = (const float*)d_in[1];
  const float* Wl = (const float*)d_in[2];
  const float* bl = (const float*)d_in[3];
  const float* Wr = (const float*)d_in[4];
  const int* edge_ap = (const int*)d_in[5];
  const int* edge_pa = (const int*)d_in[6];

  uint* selfA = (uint*)d_out;
  uint* selfP = selfA + (size_t)NNODES * DD;
  float* outA = (float*)d_out;
  float* outP = outA + (size_t)NNODES * DD;

  char* wsp = (char*)d_ws;
  ushort* aggPhi = (ushort*)wsp; wsp += (size_t)NNODES * DD * 2;
  ushort* aggPlo = (ushort*)wsp; wsp += (size_t)NNODES * DD * 2;
  ushort* aggAhi = (ushort*)wsp; wsp += (size_t)NNODES * DD * 2;
  ushort* aggAlo = (ushort*)wsp; wsp += (size_t)NNODES * DD * 2;
  ushort* WhiSw = (ushort*)wsp;  wsp += (size_t)163840 * 8 * 2;
  ushort* WloSw = (ushort*)wsp;  wsp += (size_t)163840 * 8 * 2;
  int* offAP = (int*)wsp;        wsp += (size_t)(NNODES + 1) * 4;
  int* offPA = (int*)wsp;        wsp += (size_t)(NNODES + 1) * 4;
  int* cur   = (int*)wsp;        wsp += (size_t)2 * NNODES * 4;
  int* srcAP = (int*)wsp;        wsp += (size_t)NEDGES * 4;
  int* srcPA = (int*)wsp;        wsp += (size_t)NEDGES * 4;

  hipMemsetAsync(offAP, 0, ((size_t)(NNODES + 1) * 2 + 2 * NNODES) * 4, stream);

  dim3 b256(256);
  dim3 gE((NEDGES + 255) / 256);
  hist_kernel<<<gE, b256, 0, stream>>>(edge_ap + NEDGES, NEDGES, offAP);
  hist_kernel<<<gE, b256, 0, stream>>>(edge_pa + NEDGES, NEDGES, offPA);
  scan_kernel<<<1, 1024, 0, stream>>>(offAP, NNODES + 1);
  scan_kernel<<<1, 1024, 0, stream>>>(offPA, NNODES + 1);
  fill_kernel<<<gE, b256, 0, stream>>>(edge_ap, edge_ap + NEDGES, NEDGES, offAP, cur, srcAP);
  fill_kernel<<<gE, b256, 0, stream>>>(edge_pa, edge_pa + NEDGES, NEDGES, offPA, cur + NNODES, srcPA);

  conv_w_sw<<<640, b256, 0, stream>>>(Wl, Wr, WhiSw, WloSw);
  conv_x<<<(NNODES * DD + 255) / 256, b256, 0, stream>>>(x_author, selfA, NNODES * DD);
  conv_x<<<(NNODES * DD + 255) / 256, b256, 0, stream>>>(x_paper, selfP, NNODES * DD);

  dim3 gAgg((NNODES + 3) / 4);
  dim3 gGemm((NNODES + 127) / 128);
  dim3 b512(512);

  for (int l = 0; l < NLAYERS; ++l) {
    int donorm = (l < NLAYERS - 1) ? 1 : 0;
    size_t p0 = (size_t)(l * 2 + 0);
    size_t p1 = (size_t)(l * 2 + 1);

    sage_agg2<<<gAgg, b256, 0, stream>>>(selfA, offAP, srcAP, aggPhi, aggPlo, NNODES);
    sage_agg2<<<gAgg, b256, 0, stream>>>(selfP, offPA, srcPA, aggAhi, aggAlo, NNODES);

    sage_gemm_v3<<<gGemm, b512, 0, stream>>>(
        aggPhi, aggPlo, selfP, WhiSw + p0 * 131072, WloSw + p0 * 131072,
        bl + p0 * DD, outP, selfP, NNODES, donorm);
    sage_gemm_v3<<<gGemm, b512, 0, stream>>>(
        aggAhi, aggAlo, selfA, WhiSw + p1 * 131072, WloSw + p1 * 131072,
        bl + p1 * DD, outA, selfA, NNODES, donorm);
  }
}